// Round 1
// baseline (637.057 us; speedup 1.0000x reference)
//
#include <hip/hip_runtime.h>
#include <hip/hip_bf16.h>

#define CB 16       // batch
#define CC 256      // embed
#define CH 64
#define CW 64
#define CN 4096     // H*W
#define NHEADS 8
#define NPOINTS 4
#define HDIM 32     // CC/NHEADS

// ---------------- PE table: pe[c][n] ----------------
__global__ __launch_bounds__(256) void pe_kernel(float* __restrict__ pe) {
    int idx = blockIdx.x * 256 + threadIdx.x;   // c*CN + n
    if (idx >= CC * CN) return;
    int c = idx >> 12, n = idx & (CN - 1);
    int r = n >> 6, x = n & 63;
    int i = c >> 2, t = c & 3;
    float div = expf(-logf(10000.0f) * (float)i / 64.0f);
    float arg = ((t < 2) ? (float)(x + 1) : (float)(r + 1)) * div;
    pe[idx] = (t & 1) ? cosf(arg) : sinf(arg);
}

// ---------------- value projection: v_s[b][head][n][dd] ----------------
// out[co][n] = sum_k Wv[co][k] * value[b][k][n] + bv[co]
__global__ __launch_bounds__(256) void vproj_kernel(const float* __restrict__ value,
                                                    const float* __restrict__ Wv,
                                                    const float* __restrict__ bv,
                                                    float* __restrict__ v_s) {
    int n0 = blockIdx.x * 64;
    int co0 = blockIdx.y * 64;
    int b = blockIdx.z;
    __shared__ float As[16][64];
    __shared__ float Ws[16][64];
    int tid = threadIdx.x;
    int tx = tid & 15, ty = tid >> 4;
    float acc[4][4] = {};
    const float* Ab = value + (size_t)b * CC * CN;
    for (int k0 = 0; k0 < CC; k0 += 16) {
        for (int idx = tid; idx < 16 * 64; idx += 256) {
            int kk = idx >> 6, nn = idx & 63;
            As[kk][nn] = Ab[(size_t)(k0 + kk) * CN + n0 + nn];
        }
        for (int idx = tid; idx < 64 * 16; idx += 256) {
            int cc = idx >> 4, kk = idx & 15;
            Ws[kk][cc] = Wv[(size_t)(co0 + cc) * CC + k0 + kk];
        }
        __syncthreads();
        for (int kk = 0; kk < 16; ++kk) {
            float a[4], w[4];
#pragma unroll
            for (int j = 0; j < 4; ++j) a[j] = As[kk][tx * 4 + j];
#pragma unroll
            for (int i = 0; i < 4; ++i) w[i] = Ws[kk][ty * 4 + i];
#pragma unroll
            for (int i = 0; i < 4; ++i)
#pragma unroll
                for (int j = 0; j < 4; ++j) acc[i][j] += w[i] * a[j];
        }
        __syncthreads();
    }
#pragma unroll
    for (int i = 0; i < 4; ++i) {
        int co = co0 + ty * 4 + i;
        int head = co >> 5, dd = co & 31;
        float bias = bv[co];
#pragma unroll
        for (int j = 0; j < 4; ++j) {
            int n = n0 + tx * 4 + j;
            v_s[(((size_t)b * NHEADS + head) * CN + n) * HDIM + dd] = acc[i][j] + bias;
        }
    }
}

// ---------------- offsets + attn logits: oa[b][n][96] ----------------
// j<64: W_off row j; j>=64: W_attn row j-64. A[k][n] = query[b][k][n] + pe[k][n]
__global__ __launch_bounds__(256) void offattn_kernel(const float* __restrict__ query,
                                                      const float* __restrict__ pe,
                                                      const float* __restrict__ Woff,
                                                      const float* __restrict__ boff,
                                                      const float* __restrict__ Wattn,
                                                      const float* __restrict__ battn,
                                                      float* __restrict__ oa) {
    int n0 = blockIdx.x * 64;
    int j0 = blockIdx.y * 32;
    int b = blockIdx.z;
    __shared__ float As[16][64];
    __shared__ float Ws[16][32];
    int tid = threadIdx.x;
    int tx = tid & 15, ty = tid >> 4;   // ty: 0..15, 2 j's each
    float acc[2][4] = {};
    const float* Qb = query + (size_t)b * CC * CN;
    for (int k0 = 0; k0 < CC; k0 += 16) {
        for (int idx = tid; idx < 16 * 64; idx += 256) {
            int kk = idx >> 6, nn = idx & 63;
            size_t off = (size_t)(k0 + kk) * CN + n0 + nn;
            As[kk][nn] = Qb[off] + pe[off];
        }
        for (int idx = tid; idx < 512; idx += 256) {
            int jj = idx >> 4, kk = idx & 15;
            int j = j0 + jj;
            const float* Wrow = (j < 64) ? (Woff + (size_t)j * CC) : (Wattn + (size_t)(j - 64) * CC);
            Ws[kk][jj] = Wrow[k0 + kk];
        }
        __syncthreads();
        for (int kk = 0; kk < 16; ++kk) {
            float a[4];
#pragma unroll
            for (int j = 0; j < 4; ++j) a[j] = As[kk][tx * 4 + j];
            float w0 = Ws[kk][ty * 2], w1 = Ws[kk][ty * 2 + 1];
#pragma unroll
            for (int j = 0; j < 4; ++j) { acc[0][j] += w0 * a[j]; acc[1][j] += w1 * a[j]; }
        }
        __syncthreads();
    }
#pragma unroll
    for (int i = 0; i < 2; ++i) {
        int j = j0 + ty * 2 + i;
        float bias = (j < 64) ? boff[j] : battn[j - 64];
#pragma unroll
        for (int jj = 0; jj < 4; ++jj) {
            int n = n0 + tx * 4 + jj;
            oa[((size_t)b * CN + n) * 96 + j] = acc[i][jj] + bias;
        }
    }
}

// ---------------- sampling: s[b][n][c] ----------------
__global__ __launch_bounds__(256) void sample_kernel(const float* __restrict__ oa,
                                                     const float* __restrict__ v_s,
                                                     float* __restrict__ s) {
    int bn = blockIdx.x;            // b*CN + n
    int b = bn >> 12, n = bn & (CN - 1);
    int tid = threadIdx.x;
    int head = tid >> 5, dd = tid & 31;
    const float* oarow = oa + (size_t)bn * 96;
    // softmax over 4 points (computed redundantly per lane; broadcast loads)
    float logits[NPOINTS];
    float m = -1e30f;
#pragma unroll
    for (int p = 0; p < NPOINTS; ++p) {
        logits[p] = oarow[64 + head * 4 + p];
        m = fmaxf(m, logits[p]);
    }
    float sum = 0.f, wts[NPOINTS];
#pragma unroll
    for (int p = 0; p < NPOINTS; ++p) { wts[p] = expf(logits[p] - m); sum += wts[p]; }
    float inv = 1.0f / sum;

    float ref0 = (float)(n & 63) * (1.0f / 63.0f);
    float ref1 = (float)(n >> 6) * (1.0f / 63.0f);
    const float* vb = v_s + (((size_t)b * NHEADS + head) * CN) * HDIM;

    float out = 0.f;
#pragma unroll
    for (int p = 0; p < NPOINTS; ++p) {
        float off0 = oarow[head * 8 + p * 2 + 0];
        float off1 = oarow[head * 8 + p * 2 + 1];
        float ix = (ref0 + off0 * (1.0f / 64.0f)) * 64.0f - 0.5f;
        float iy = (ref1 + off1 * (1.0f / 64.0f)) * 64.0f - 0.5f;
        float x0f = floorf(ix), y0f = floorf(iy);
        float wx = ix - x0f, wy = iy - y0f;
        int x0 = (int)x0f, y0 = (int)y0f;
        float g00 = 0.f, g01 = 0.f, g10 = 0.f, g11 = 0.f;
        if (y0 >= 0 && y0 < CH) {
            if (x0 >= 0 && x0 < CW)         g00 = vb[(size_t)(y0 * CW + x0) * HDIM + dd];
            if (x0 + 1 >= 0 && x0 + 1 < CW) g01 = vb[(size_t)(y0 * CW + x0 + 1) * HDIM + dd];
        }
        if (y0 + 1 >= 0 && y0 + 1 < CH) {
            if (x0 >= 0 && x0 < CW)         g10 = vb[(size_t)((y0 + 1) * CW + x0) * HDIM + dd];
            if (x0 + 1 >= 0 && x0 + 1 < CW) g11 = vb[(size_t)((y0 + 1) * CW + x0 + 1) * HDIM + dd];
        }
        float bil = (1.f - wx) * (1.f - wy) * g00 + wx * (1.f - wy) * g01 +
                    (1.f - wx) * wy * g10 + wx * wy * g11;
        out += (wts[p] * inv) * bil;
    }
    s[(size_t)bn * CC + tid] = out;
}

// ---------------- output projection + residuals ----------------
// out[b][c][n] = sum_k Wout[c][k]*s[b][n][k] + bout[c] + 2*(query[b][c][n] + pe[c][n])
__global__ __launch_bounds__(256) void outproj_kernel(const float* __restrict__ s,
                                                      const float* __restrict__ Wout,
                                                      const float* __restrict__ bout,
                                                      const float* __restrict__ query,
                                                      const float* __restrict__ pe,
                                                      float* __restrict__ out) {
    int n0 = blockIdx.x * 64;
    int c0 = blockIdx.y * 64;
    int b = blockIdx.z;
    __shared__ float As[16][64];
    __shared__ float Ws[16][64];
    int tid = threadIdx.x;
    int tx = tid & 15, ty = tid >> 4;
    float acc[4][4] = {};
    const float* sb = s + (size_t)b * CN * CC;
    for (int k0 = 0; k0 < CC; k0 += 16) {
        for (int idx = tid; idx < 1024; idx += 256) {
            int nn = idx >> 4, kk = idx & 15;
            As[kk][nn] = sb[(size_t)(n0 + nn) * CC + k0 + kk];
        }
        for (int idx = tid; idx < 1024; idx += 256) {
            int cc = idx >> 4, kk = idx & 15;
            Ws[kk][cc] = Wout[(size_t)(c0 + cc) * CC + k0 + kk];
        }
        __syncthreads();
        for (int kk = 0; kk < 16; ++kk) {
            float a[4], w[4];
#pragma unroll
            for (int j = 0; j < 4; ++j) a[j] = As[kk][tx * 4 + j];
#pragma unroll
            for (int i = 0; i < 4; ++i) w[i] = Ws[kk][ty * 4 + i];
#pragma unroll
            for (int i = 0; i < 4; ++i)
#pragma unroll
                for (int j = 0; j < 4; ++j) acc[i][j] += w[i] * a[j];
        }
        __syncthreads();
    }
#pragma unroll
    for (int i = 0; i < 4; ++i) {
        int c = c0 + ty * 4 + i;
        float bias = bout[c];
#pragma unroll
        for (int j = 0; j < 4; ++j) {
            int n = n0 + tx * 4 + j;
            size_t qi = ((size_t)b * CC + c) * CN + n;
            out[qi] = acc[i][j] + bias + 2.0f * (query[qi] + pe[(size_t)c * CN + n]);
        }
    }
}

extern "C" void kernel_launch(void* const* d_in, const int* in_sizes, int n_in,
                              void* d_out, int out_size, void* d_ws, size_t ws_size,
                              hipStream_t stream) {
    const float* query = (const float*)d_in[0];
    const float* value = (const float*)d_in[1];
    const float* W_off = (const float*)d_in[2];
    const float* b_off = (const float*)d_in[3];
    const float* W_attn = (const float*)d_in[4];
    const float* b_attn = (const float*)d_in[5];
    const float* W_val = (const float*)d_in[6];
    const float* b_val = (const float*)d_in[7];
    const float* W_out = (const float*)d_in[8];
    const float* b_out = (const float*)d_in[9];
    float* out = (float*)d_out;

    float* ws = (float*)d_ws;
    float* pe = ws;                                     // 256*4096      = 1,048,576
    float* v_s = pe + (size_t)CC * CN;                  // 16*8*4096*32  = 16,777,216
    float* oa = v_s + (size_t)CB * NHEADS * CN * HDIM;  // 16*4096*96    = 6,291,456
    float* s = oa + (size_t)CB * CN * 96;               // 16*4096*256   = 16,777,216

    pe_kernel<<<dim3((CC * CN + 255) / 256), dim3(256), 0, stream>>>(pe);
    vproj_kernel<<<dim3(CN / 64, CC / 64, CB), dim3(256), 0, stream>>>(value, W_val, b_val, v_s);
    offattn_kernel<<<dim3(CN / 64, 3, CB), dim3(256), 0, stream>>>(query, pe, W_off, b_off,
                                                                   W_attn, b_attn, oa);
    sample_kernel<<<dim3(CB * CN), dim3(256), 0, stream>>>(oa, v_s, s);
    outproj_kernel<<<dim3(CN / 64, CC / 64, CB), dim3(256), 0, stream>>>(s, W_out, b_out,
                                                                         query, pe, out);
}

// Round 2
// 387.677 us; speedup vs baseline: 1.6433x; 1.6433x over previous
//
#include <hip/hip_runtime.h>
#include <hip/hip_bf16.h>

typedef __bf16 bf16;
typedef bf16 bf16x8 __attribute__((ext_vector_type(8)));
typedef bf16 bf16x4 __attribute__((ext_vector_type(4)));
typedef float f32x4 __attribute__((ext_vector_type(4)));

#define CB 16
#define CC 256
#define CH 64
#define CW 64
#define CN 4096
#define NHEADS 8
#define NPOINTS 4
#define HDIM 32

#define MFMA16(a, b, c) __builtin_amdgcn_mfma_f32_16x16x32_bf16(a, b, c, 0, 0, 0)

// ---------------- PE table: pe[c][n] (f32) ----------------
__global__ __launch_bounds__(256) void pe_kernel(float* __restrict__ pe) {
    int idx = blockIdx.x * 256 + threadIdx.x;
    if (idx >= CC * CN) return;
    int c = idx >> 12, n = idx & (CN - 1);
    int r = n >> 6, x = n & 63;
    int i = c >> 2, t = c & 3;
    float div = expf(-logf(10000.0f) * (float)i / 64.0f);
    float arg = ((t < 2) ? (float)(x + 1) : (float)(r + 1)) * div;
    pe[idx] = (t & 1) ? cosf(arg) : sinf(arg);
}

// ---------------- weight packing to bf16 ----------------
__global__ __launch_bounds__(256) void pack_w(const float* __restrict__ Wv,
                                              const float* __restrict__ Woff,
                                              const float* __restrict__ Wattn,
                                              const float* __restrict__ Wout,
                                              bf16* __restrict__ Wv_bf,
                                              bf16* __restrict__ W96_bf,
                                              bf16* __restrict__ Wout_bf) {
    int i = blockIdx.x * 256 + threadIdx.x;
    if (i < CC * CC) {
        Wv_bf[i] = (bf16)Wv[i];
        Wout_bf[i] = (bf16)Wout[i];
    }
    if (i < 96 * CC) {
        W96_bf[i] = (bf16)((i < 64 * CC) ? Woff[i] : Wattn[i - 64 * CC]);
    }
}

// ---------------- transpose + cvt: in[b][k][n] f32 (+pe) -> out[b][n][k] bf16 ----------------
template <bool ADD_PE>
__global__ __launch_bounds__(256) void transpose_cvt(const float* __restrict__ in,
                                                     const float* __restrict__ pe,
                                                     bf16* __restrict__ outp) {
    __shared__ float tile[64][65];
    int n0 = blockIdx.x * 64, k0 = blockIdx.y * 64, b = blockIdx.z;
    int tid = threadIdx.x;
    int tr = tid >> 4, tc = tid & 15;
    const float* src = in + ((size_t)b * CC + k0) * CN + n0;
#pragma unroll
    for (int p = 0; p < 4; ++p) {
        int k = p * 16 + tr;
        f32x4 v = *(const f32x4*)&src[(size_t)k * CN + tc * 4];
        if (ADD_PE) {
            f32x4 pv = *(const f32x4*)&pe[(size_t)(k0 + k) * CN + n0 + tc * 4];
            v += pv;
        }
#pragma unroll
        for (int j = 0; j < 4; ++j) tile[k][tc * 4 + j] = v[j];
    }
    __syncthreads();
#pragma unroll
    for (int p = 0; p < 4; ++p) {
        int n = p * 16 + tr;
        bf16x4 o;
#pragma unroll
        for (int j = 0; j < 4; ++j) o[j] = (bf16)tile[tc * 4 + j][n];
        *(bf16x4*)&outp[((size_t)b * CN + n0 + n) * CC + k0 + tc * 4] = o;
    }
}

// ---------------- shared staging helper: rows of [*][256] bf16 -> lds[row][72] ----------------
__device__ __forceinline__ void stage_rows(const bf16* __restrict__ src, bf16 (*lds)[72],
                                           int nrows, int tid) {
    for (int i = tid; i < nrows * 8; i += 256) {
        int row = i >> 3, ch = i & 7;
        uint4 v = *reinterpret_cast<const uint4*>(src + (size_t)row * CC + ch * 8);
        *reinterpret_cast<uint4*>(&lds[row][ch * 8]) = v;
    }
}

// ---------------- value projection: Wv[256][256] x act[b][n][256] -> v_s bf16 [b][h][n][dd] ----
__global__ __launch_bounds__(256) void vproj_mfma(const bf16* __restrict__ Wv,
                                                  const float* __restrict__ bv,
                                                  const bf16* __restrict__ act,
                                                  bf16* __restrict__ v_s) {
    __shared__ bf16 As[128][72];
    __shared__ bf16 Bs[128][72];
    int tid = threadIdx.x, lane = tid & 63, wave = tid >> 6;
    int wm = wave >> 1, wn = wave & 1, g = lane >> 4, lr = lane & 15;
    int n0 = blockIdx.x * 128, m0 = blockIdx.y * 128, b = blockIdx.z;
    const bf16* actb = act + (size_t)b * CN * CC;
    f32x4 acc[4][4] = {};
    for (int k0 = 0; k0 < CC; k0 += 64) {
        stage_rows(Wv + (size_t)m0 * CC + k0, As, 128, tid);
        stage_rows(actb + (size_t)n0 * CC + k0, Bs, 128, tid);
        __syncthreads();
#pragma unroll
        for (int ks = 0; ks < 2; ++ks) {
            bf16x8 af[4], bfr[4];
#pragma unroll
            for (int mf = 0; mf < 4; ++mf)
                af[mf] = *(const bf16x8*)&As[wm * 64 + mf * 16 + lr][ks * 32 + g * 8];
#pragma unroll
            for (int nf = 0; nf < 4; ++nf)
                bfr[nf] = *(const bf16x8*)&Bs[wn * 64 + nf * 16 + lr][ks * 32 + g * 8];
#pragma unroll
            for (int mf = 0; mf < 4; ++mf)
#pragma unroll
                for (int nf = 0; nf < 4; ++nf)
                    acc[mf][nf] = MFMA16(af[mf], bfr[nf], acc[mf][nf]);
        }
        __syncthreads();
    }
#pragma unroll
    for (int mf = 0; mf < 4; ++mf) {
        int co = m0 + wm * 64 + mf * 16 + g * 4;
        int head = co >> 5, dd = co & 31;
        float b0 = bv[co], b1 = bv[co + 1], b2 = bv[co + 2], b3 = bv[co + 3];
#pragma unroll
        for (int nf = 0; nf < 4; ++nf) {
            int n = n0 + wn * 64 + nf * 16 + lr;
            bf16x4 o;
            o[0] = (bf16)(acc[mf][nf][0] + b0);
            o[1] = (bf16)(acc[mf][nf][1] + b1);
            o[2] = (bf16)(acc[mf][nf][2] + b2);
            o[3] = (bf16)(acc[mf][nf][3] + b3);
            *(bf16x4*)&v_s[(((size_t)b * NHEADS + head) * CN + n) * HDIM + dd] = o;
        }
    }
}

// ---------------- off+attn: W96[96][256] x qpe[b][n][256] -> oa f32 [b][n][96] ----------------
__global__ __launch_bounds__(256) void offattn_mfma(const bf16* __restrict__ W96,
                                                    const float* __restrict__ boff,
                                                    const float* __restrict__ battn,
                                                    const bf16* __restrict__ qpe,
                                                    float* __restrict__ oa) {
    __shared__ bf16 As[96][72];
    __shared__ bf16 Bs[128][72];
    int tid = threadIdx.x, lane = tid & 63, wave = tid >> 6;
    int wm = wave >> 1, wn = wave & 1, g = lane >> 4, lr = lane & 15;
    int n0 = blockIdx.x * 128, b = blockIdx.z;
    const bf16* qb = qpe + (size_t)b * CN * CC;
    f32x4 acc[3][4] = {};
    for (int k0 = 0; k0 < CC; k0 += 64) {
        stage_rows(W96 + k0, As, 96, tid);
        stage_rows(qb + (size_t)n0 * CC + k0, Bs, 128, tid);
        __syncthreads();
#pragma unroll
        for (int ks = 0; ks < 2; ++ks) {
            bf16x8 af[3], bfr[4];
#pragma unroll
            for (int mf = 0; mf < 3; ++mf)
                af[mf] = *(const bf16x8*)&As[wm * 48 + mf * 16 + lr][ks * 32 + g * 8];
#pragma unroll
            for (int nf = 0; nf < 4; ++nf)
                bfr[nf] = *(const bf16x8*)&Bs[wn * 64 + nf * 16 + lr][ks * 32 + g * 8];
#pragma unroll
            for (int mf = 0; mf < 3; ++mf)
#pragma unroll
                for (int nf = 0; nf < 4; ++nf)
                    acc[mf][nf] = MFMA16(af[mf], bfr[nf], acc[mf][nf]);
        }
        __syncthreads();
    }
#pragma unroll
    for (int mf = 0; mf < 3; ++mf) {
        int j = wm * 48 + mf * 16 + g * 4;
        f32x4 bias;
#pragma unroll
        for (int r = 0; r < 4; ++r) {
            int jj = j + r;
            bias[r] = (jj < 64) ? boff[jj] : battn[jj - 64];
        }
#pragma unroll
        for (int nf = 0; nf < 4; ++nf) {
            int n = n0 + wn * 64 + nf * 16 + lr;
            f32x4 o = acc[mf][nf] + bias;
            *(f32x4*)&oa[((size_t)b * CN + n) * 96 + j] = o;
        }
    }
}

// ---------------- sampling: softmax + bilinear gather -> s bf16 [b][n][256] ----------------
__global__ __launch_bounds__(256) void sample_kernel(const float* __restrict__ oa,
                                                     const bf16* __restrict__ v_s,
                                                     bf16* __restrict__ s) {
    int bn = blockIdx.x;
    int b = bn >> 12, n = bn & (CN - 1);
    int tid = threadIdx.x;
    int head = tid >> 5, dd = tid & 31;
    const float* oarow = oa + (size_t)bn * 96;
    float logits[NPOINTS];
    float m = -1e30f;
#pragma unroll
    for (int p = 0; p < NPOINTS; ++p) {
        logits[p] = oarow[64 + head * 4 + p];
        m = fmaxf(m, logits[p]);
    }
    float sum = 0.f, wts[NPOINTS];
#pragma unroll
    for (int p = 0; p < NPOINTS; ++p) { wts[p] = expf(logits[p] - m); sum += wts[p]; }
    float inv = 1.0f / sum;

    float ref0 = (float)(n & 63) * (1.0f / 63.0f);
    float ref1 = (float)(n >> 6) * (1.0f / 63.0f);
    const bf16* vb = v_s + (((size_t)b * NHEADS + head) * CN) * HDIM;

    float out = 0.f;
#pragma unroll
    for (int p = 0; p < NPOINTS; ++p) {
        float off0 = oarow[head * 8 + p * 2 + 0];
        float off1 = oarow[head * 8 + p * 2 + 1];
        float ix = (ref0 + off0 * (1.0f / 64.0f)) * 64.0f - 0.5f;
        float iy = (ref1 + off1 * (1.0f / 64.0f)) * 64.0f - 0.5f;
        float x0f = floorf(ix), y0f = floorf(iy);
        float wx = ix - x0f, wy = iy - y0f;
        int x0 = (int)x0f, y0 = (int)y0f;
        float g00 = 0.f, g01 = 0.f, g10 = 0.f, g11 = 0.f;
        if (y0 >= 0 && y0 < CH) {
            if (x0 >= 0 && x0 < CW)         g00 = (float)vb[(size_t)(y0 * CW + x0) * HDIM + dd];
            if (x0 + 1 >= 0 && x0 + 1 < CW) g01 = (float)vb[(size_t)(y0 * CW + x0 + 1) * HDIM + dd];
        }
        if (y0 + 1 >= 0 && y0 + 1 < CH) {
            if (x0 >= 0 && x0 < CW)         g10 = (float)vb[(size_t)((y0 + 1) * CW + x0) * HDIM + dd];
            if (x0 + 1 >= 0 && x0 + 1 < CW) g11 = (float)vb[(size_t)((y0 + 1) * CW + x0 + 1) * HDIM + dd];
        }
        float bil = (1.f - wx) * (1.f - wy) * g00 + wx * (1.f - wy) * g01 +
                    (1.f - wx) * wy * g10 + wx * wy * g11;
        out += (wts[p] * inv) * bil;
    }
    s[(size_t)bn * CC + tid] = (bf16)out;
}

// ---------------- output proj: s[b][n][256] x Wout[256][256] + residual -> out[b][c][n] -----
__global__ __launch_bounds__(256) void outproj_mfma(const bf16* __restrict__ s_t,
                                                    const bf16* __restrict__ Wout,
                                                    const float* __restrict__ bout,
                                                    const float* __restrict__ query,
                                                    const float* __restrict__ pe,
                                                    float* __restrict__ out) {
    __shared__ bf16 As[128][72];
    __shared__ bf16 Bs[128][72];
    int tid = threadIdx.x, lane = tid & 63, wave = tid >> 6;
    int wm = wave >> 1, wn = wave & 1, g = lane >> 4, lr = lane & 15;
    int n0 = blockIdx.x * 128, c0 = blockIdx.y * 128, b = blockIdx.z;
    const bf16* sb = s_t + (size_t)b * CN * CC;
    f32x4 acc[4][4] = {};
    for (int k0 = 0; k0 < CC; k0 += 64) {
        stage_rows(sb + (size_t)n0 * CC + k0, As, 128, tid);
        stage_rows(Wout + (size_t)c0 * CC + k0, Bs, 128, tid);
        __syncthreads();
#pragma unroll
        for (int ks = 0; ks < 2; ++ks) {
            bf16x8 af[4], bfr[4];
#pragma unroll
            for (int mf = 0; mf < 4; ++mf)
                af[mf] = *(const bf16x8*)&As[wm * 64 + mf * 16 + lr][ks * 32 + g * 8];
#pragma unroll
            for (int nf = 0; nf < 4; ++nf)
                bfr[nf] = *(const bf16x8*)&Bs[wn * 64 + nf * 16 + lr][ks * 32 + g * 8];
#pragma unroll
            for (int mf = 0; mf < 4; ++mf)
#pragma unroll
                for (int nf = 0; nf < 4; ++nf)
                    acc[mf][nf] = MFMA16(af[mf], bfr[nf], acc[mf][nf]);
        }
        __syncthreads();
    }
#pragma unroll
    for (int mf = 0; mf < 4; ++mf) {
        int n = n0 + wm * 64 + mf * 16 + g * 4;
#pragma unroll
        for (int nf = 0; nf < 4; ++nf) {
            int c = c0 + wn * 64 + nf * 16 + lr;
            size_t base = ((size_t)b * CC + c) * CN + n;
            f32x4 q4 = *(const f32x4*)&query[base];
            f32x4 p4 = *(const f32x4*)&pe[(size_t)c * CN + n];
            float bias = bout[c];
            f32x4 r = acc[mf][nf];
#pragma unroll
            for (int j = 0; j < 4; ++j) r[j] = r[j] + bias + 2.0f * (q4[j] + p4[j]);
            *(f32x4*)&out[base] = r;
        }
    }
}

extern "C" void kernel_launch(void* const* d_in, const int* in_sizes, int n_in,
                              void* d_out, int out_size, void* d_ws, size_t ws_size,
                              hipStream_t stream) {
    const float* query = (const float*)d_in[0];
    const float* value = (const float*)d_in[1];
    const float* W_off = (const float*)d_in[2];
    const float* b_off = (const float*)d_in[3];
    const float* W_attn = (const float*)d_in[4];
    const float* b_attn = (const float*)d_in[5];
    const float* W_val = (const float*)d_in[6];
    const float* b_val = (const float*)d_in[7];
    const float* W_out = (const float*)d_in[8];
    const float* b_out = (const float*)d_in[9];
    float* out = (float*)d_out;

    char* p = (char*)d_ws;
    float* pe = (float*)p;            p += (size_t)CC * CN * 4;            // 4 MB
    bf16* Wv_bf = (bf16*)p;           p += (size_t)CC * CC * 2;            // 128 KB
    bf16* Wout_bf = (bf16*)p;         p += (size_t)CC * CC * 2;            // 128 KB
    bf16* W96_bf = (bf16*)p;          p += (size_t)96 * CC * 2 + 256;      // 48 KB
    bf16* val_t = (bf16*)p;           p += (size_t)CB * CN * CC * 2;       // 32 MB
    bf16* qpe_t = (bf16*)p;           p += (size_t)CB * CN * CC * 2;       // 32 MB
    bf16* v_s = (bf16*)p;             p += (size_t)CB * NHEADS * CN * HDIM * 2; // 32 MB
    float* oa = (float*)p;            p += (size_t)CB * CN * 96 * 4;       // 24 MB
    bf16* s_t = (bf16*)p;             p += (size_t)CB * CN * CC * 2;       // 32 MB

    pe_kernel<<<dim3((CC * CN + 255) / 256), dim3(256), 0, stream>>>(pe);
    pack_w<<<dim3(256), dim3(256), 0, stream>>>(W_val, W_off, W_attn, W_out,
                                                Wv_bf, W96_bf, Wout_bf);
    transpose_cvt<false><<<dim3(CN / 64, CC / 64, CB), dim3(256), 0, stream>>>(value, nullptr, val_t);
    transpose_cvt<true><<<dim3(CN / 64, CC / 64, CB), dim3(256), 0, stream>>>(query, pe, qpe_t);
    vproj_mfma<<<dim3(CN / 128, CC / 128, CB), dim3(256), 0, stream>>>(Wv_bf, b_val, val_t, v_s);
    offattn_mfma<<<dim3(CN / 128, 1, CB), dim3(256), 0, stream>>>(W96_bf, b_off, b_attn, qpe_t, oa);
    sample_kernel<<<dim3(CB * CN), dim3(256), 0, stream>>>(oa, v_s, s_t);
    outproj_mfma<<<dim3(CN / 128, CC / 128, CB), dim3(256), 0, stream>>>(s_t, Wout_bf, b_out,
                                                                         query, pe, out);
}

// Round 3
// 197.536 us; speedup vs baseline: 3.2250x; 1.9626x over previous
//
#include <hip/hip_runtime.h>
#include <hip/hip_bf16.h>

typedef __bf16 bf16;
typedef bf16 bf16x8 __attribute__((ext_vector_type(8)));
typedef bf16 bf16x4 __attribute__((ext_vector_type(4)));
typedef float f32x4 __attribute__((ext_vector_type(4)));

#define CB 16
#define CC 256
#define CH 64
#define CW 64
#define CN 4096
#define NHEADS 8
#define NPOINTS 4
#define HDIM 32
#define SNB 8   // n's per sampling block

#define MFMA16(a, b, c) __builtin_amdgcn_mfma_f32_16x16x32_bf16(a, b, c, 0, 0, 0)

// ---------------- PE table: pe[c][n] (f32) ----------------
__global__ __launch_bounds__(256) void pe_kernel(float* __restrict__ pe) {
    int idx = blockIdx.x * 256 + threadIdx.x;
    if (idx >= CC * CN) return;
    int c = idx >> 12, n = idx & (CN - 1);
    int r = n >> 6, x = n & 63;
    int i = c >> 2, t = c & 3;
    float div = __expf(-logf(10000.0f) * (float)i / 64.0f);
    float arg = ((t < 2) ? (float)(x + 1) : (float)(r + 1)) * div;
    pe[idx] = (t & 1) ? cosf(arg) : sinf(arg);
}

// ---------------- weight packing to bf16 ----------------
__global__ __launch_bounds__(256) void pack_w(const float* __restrict__ Wv,
                                              const float* __restrict__ Woff,
                                              const float* __restrict__ Wattn,
                                              const float* __restrict__ Wout,
                                              bf16* __restrict__ Wv_bf,
                                              bf16* __restrict__ W96_bf,
                                              bf16* __restrict__ Wout_bf) {
    int i = blockIdx.x * 256 + threadIdx.x;
    if (i < CC * CC) {
        Wv_bf[i] = (bf16)Wv[i];
        Wout_bf[i] = (bf16)Wout[i];
    }
    if (i < 96 * CC) {
        W96_bf[i] = (bf16)((i < 64 * CC) ? Woff[i] : Wattn[i - 64 * CC]);
    }
}

// ---------------- transpose + cvt: in[b][k][n] f32 (+pe) -> out[b][n][k] bf16 ----------------
template <bool ADD_PE>
__global__ __launch_bounds__(256) void transpose_cvt(const float* __restrict__ in,
                                                     const float* __restrict__ pe,
                                                     bf16* __restrict__ outp) {
    __shared__ float tile[64][65];
    int n0 = blockIdx.x * 64, k0 = blockIdx.y * 64, b = blockIdx.z;
    int tid = threadIdx.x;
    int tr = tid >> 4, tc = tid & 15;
    const float* src = in + ((size_t)b * CC + k0) * CN + n0;
#pragma unroll
    for (int p = 0; p < 4; ++p) {
        int k = p * 16 + tr;
        f32x4 v = *(const f32x4*)&src[(size_t)k * CN + tc * 4];
        if (ADD_PE) {
            f32x4 pv = *(const f32x4*)&pe[(size_t)(k0 + k) * CN + n0 + tc * 4];
            v += pv;
        }
#pragma unroll
        for (int j = 0; j < 4; ++j) tile[k][tc * 4 + j] = v[j];
    }
    __syncthreads();
#pragma unroll
    for (int p = 0; p < 4; ++p) {
        int n = p * 16 + tr;
        bf16x4 o;
#pragma unroll
        for (int j = 0; j < 4; ++j) o[j] = (bf16)tile[tc * 4 + j][n];
        *(bf16x4*)&outp[((size_t)b * CN + n0 + n) * CC + k0 + tc * 4] = o;
    }
}

// ---------------- shared staging helper: rows of [*][256] bf16 -> lds[row][72] ----------------
__device__ __forceinline__ void stage_rows(const bf16* __restrict__ src, bf16 (*lds)[72],
                                           int nrows, int tid) {
    for (int i = tid; i < nrows * 8; i += 256) {
        int row = i >> 3, ch = i & 7;
        uint4 v = *reinterpret_cast<const uint4*>(src + (size_t)row * CC + ch * 8);
        *reinterpret_cast<uint4*>(&lds[row][ch * 8]) = v;
    }
}

// ---------------- value projection: Wv[256][256] x act[b][n][256] -> v_s bf16 [b][h][n][dd] ----
__global__ __launch_bounds__(256) void vproj_mfma(const bf16* __restrict__ Wv,
                                                  const float* __restrict__ bv,
                                                  const bf16* __restrict__ act,
                                                  bf16* __restrict__ v_s) {
    __shared__ bf16 As[128][72];
    __shared__ bf16 Bs[128][72];
    int tid = threadIdx.x, lane = tid & 63, wave = tid >> 6;
    int wm = wave >> 1, wn = wave & 1, g = lane >> 4, lr = lane & 15;
    int n0 = blockIdx.x * 128, m0 = blockIdx.y * 128, b = blockIdx.z;
    const bf16* actb = act + (size_t)b * CN * CC;
    f32x4 acc[4][4] = {};
    for (int k0 = 0; k0 < CC; k0 += 64) {
        stage_rows(Wv + (size_t)m0 * CC + k0, As, 128, tid);
        stage_rows(actb + (size_t)n0 * CC + k0, Bs, 128, tid);
        __syncthreads();
#pragma unroll
        for (int ks = 0; ks < 2; ++ks) {
            bf16x8 af[4], bfr[4];
#pragma unroll
            for (int mf = 0; mf < 4; ++mf)
                af[mf] = *(const bf16x8*)&As[wm * 64 + mf * 16 + lr][ks * 32 + g * 8];
#pragma unroll
            for (int nf = 0; nf < 4; ++nf)
                bfr[nf] = *(const bf16x8*)&Bs[wn * 64 + nf * 16 + lr][ks * 32 + g * 8];
#pragma unroll
            for (int mf = 0; mf < 4; ++mf)
#pragma unroll
                for (int nf = 0; nf < 4; ++nf)
                    acc[mf][nf] = MFMA16(af[mf], bfr[nf], acc[mf][nf]);
        }
        __syncthreads();
    }
#pragma unroll
    for (int mf = 0; mf < 4; ++mf) {
        int co = m0 + wm * 64 + mf * 16 + g * 4;
        int head = co >> 5, dd = co & 31;
        float b0 = bv[co], b1 = bv[co + 1], b2 = bv[co + 2], b3 = bv[co + 3];
#pragma unroll
        for (int nf = 0; nf < 4; ++nf) {
            int n = n0 + wn * 64 + nf * 16 + lr;
            bf16x4 o;
            o[0] = (bf16)(acc[mf][nf][0] + b0);
            o[1] = (bf16)(acc[mf][nf][1] + b1);
            o[2] = (bf16)(acc[mf][nf][2] + b2);
            o[3] = (bf16)(acc[mf][nf][3] + b3);
            *(bf16x4*)&v_s[(((size_t)b * NHEADS + head) * CN + n) * HDIM + dd] = o;
        }
    }
}

// ---------------- off+attn: W96[96][256] x qpe[b][n][256] -> oa f32 [b][n][96] ----------------
__global__ __launch_bounds__(256) void offattn_mfma(const bf16* __restrict__ W96,
                                                    const float* __restrict__ boff,
                                                    const float* __restrict__ battn,
                                                    const bf16* __restrict__ qpe,
                                                    float* __restrict__ oa) {
    __shared__ bf16 As[96][72];
    __shared__ bf16 Bs[128][72];
    int tid = threadIdx.x, lane = tid & 63, wave = tid >> 6;
    int wm = wave >> 1, wn = wave & 1, g = lane >> 4, lr = lane & 15;
    int n0 = blockIdx.x * 128, b = blockIdx.z;
    const bf16* qb = qpe + (size_t)b * CN * CC;
    f32x4 acc[3][4] = {};
    for (int k0 = 0; k0 < CC; k0 += 64) {
        stage_rows(W96 + k0, As, 96, tid);
        stage_rows(qb + (size_t)n0 * CC + k0, Bs, 128, tid);
        __syncthreads();
#pragma unroll
        for (int ks = 0; ks < 2; ++ks) {
            bf16x8 af[3], bfr[4];
#pragma unroll
            for (int mf = 0; mf < 3; ++mf)
                af[mf] = *(const bf16x8*)&As[wm * 48 + mf * 16 + lr][ks * 32 + g * 8];
#pragma unroll
            for (int nf = 0; nf < 4; ++nf)
                bfr[nf] = *(const bf16x8*)&Bs[wn * 64 + nf * 16 + lr][ks * 32 + g * 8];
#pragma unroll
            for (int mf = 0; mf < 3; ++mf)
#pragma unroll
                for (int nf = 0; nf < 4; ++nf)
                    acc[mf][nf] = MFMA16(af[mf], bfr[nf], acc[mf][nf]);
        }
        __syncthreads();
    }
#pragma unroll
    for (int mf = 0; mf < 3; ++mf) {
        int j = wm * 48 + mf * 16 + g * 4;
        f32x4 bias;
#pragma unroll
        for (int r = 0; r < 4; ++r) {
            int jj = j + r;
            bias[r] = (jj < 64) ? boff[jj] : battn[jj - 64];
        }
#pragma unroll
        for (int nf = 0; nf < 4; ++nf) {
            int n = n0 + wn * 64 + nf * 16 + lr;
            f32x4 o = acc[mf][nf] + bias;
            *(f32x4*)&oa[((size_t)b * CN + n) * 96 + j] = o;
        }
    }
}

// ---------------- sampling: two-phase (weights once, wide gathers) -> s bf16 [b][n][256] ----
__global__ __launch_bounds__(256) void sample_kernel(const float* __restrict__ oa,
                                                     const bf16* __restrict__ v_s,
                                                     bf16* __restrict__ s) {
    __shared__ int   lidx[SNB][NHEADS][NPOINTS][4];
    __shared__ float lwgt[SNB][NHEADS][NPOINTS][4];
    int bn0 = blockIdx.x * SNB;
    int b = bn0 >> 12;
    int tid = threadIdx.x;

    // ---- phase 1: (nl, head, p) -> fold softmax*bilinear*validity into 4 corner weights ----
    {
        int nl = tid >> 5, head = (tid >> 2) & 7, p = tid & 3;
        int bn = bn0 + nl;
        int n = bn & (CN - 1);
        const float* oarow = oa + (size_t)bn * 96;
        f32x4 lg = *(const f32x4*)&oarow[64 + head * 4];
        float m = fmaxf(fmaxf(lg[0], lg[1]), fmaxf(lg[2], lg[3]));
        float e0 = __expf(lg[0] - m), e1 = __expf(lg[1] - m);
        float e2 = __expf(lg[2] - m), e3 = __expf(lg[3] - m);
        float ep = (p == 0) ? e0 : (p == 1) ? e1 : (p == 2) ? e2 : e3;
        float a = ep / (e0 + e1 + e2 + e3);

        float off0 = oarow[head * 8 + p * 2];
        float off1 = oarow[head * 8 + p * 2 + 1];
        float ix = (float)(n & 63) * (64.0f / 63.0f) + off0 - 0.5f;
        float iy = (float)(n >> 6) * (64.0f / 63.0f) + off1 - 0.5f;
        float x0f = floorf(ix), y0f = floorf(iy);
        float wx = ix - x0f, wy = iy - y0f;
        int x0 = (int)x0f, y0 = (int)y0f;
        int x1 = x0 + 1, y1 = y0 + 1;
        float vx0 = (x0 >= 0 && x0 < CW) ? 1.f : 0.f;
        float vx1 = (x1 >= 0 && x1 < CW) ? 1.f : 0.f;
        float vy0 = (y0 >= 0 && y0 < CH) ? 1.f : 0.f;
        float vy1 = (y1 >= 0 && y1 < CH) ? 1.f : 0.f;
        int x0c = min(max(x0, 0), CW - 1), x1c = min(max(x1, 0), CW - 1);
        int y0c = min(max(y0, 0), CH - 1), y1c = min(max(y1, 0), CH - 1);
        lwgt[nl][head][p][0] = a * (1.f - wx) * (1.f - wy) * vx0 * vy0;
        lwgt[nl][head][p][1] = a * wx * (1.f - wy) * vx1 * vy0;
        lwgt[nl][head][p][2] = a * (1.f - wx) * wy * vx0 * vy1;
        lwgt[nl][head][p][3] = a * wx * wy * vx1 * vy1;
        lidx[nl][head][p][0] = (y0c * CW + x0c) * HDIM;
        lidx[nl][head][p][1] = (y0c * CW + x1c) * HDIM;
        lidx[nl][head][p][2] = (y1c * CW + x0c) * HDIM;
        lidx[nl][head][p][3] = (y1c * CW + x1c) * HDIM;
    }
    __syncthreads();

    // ---- phase 2: (nl, head, q) -> 8 channels each, 16B gathers ----
    int nl = tid >> 5, head = (tid >> 2) & 7, q = tid & 3;
    int bn = bn0 + nl;
    const bf16* vb = v_s + (((size_t)b * NHEADS + head) * CN) * HDIM + q * 8;
    float acc0 = 0.f, acc1 = 0.f, acc2 = 0.f, acc3 = 0.f;
    float acc4 = 0.f, acc5 = 0.f, acc6 = 0.f, acc7 = 0.f;
#pragma unroll
    for (int p = 0; p < NPOINTS; ++p) {
#pragma unroll
        for (int c = 0; c < 4; ++c) {
            float w = lwgt[nl][head][p][c];
            int id = lidx[nl][head][p][c];
            bf16x8 v = *(const bf16x8*)&vb[id];
            acc0 += w * (float)v[0];
            acc1 += w * (float)v[1];
            acc2 += w * (float)v[2];
            acc3 += w * (float)v[3];
            acc4 += w * (float)v[4];
            acc5 += w * (float)v[5];
            acc6 += w * (float)v[6];
            acc7 += w * (float)v[7];
        }
    }
    bf16x8 o;
    o[0] = (bf16)acc0; o[1] = (bf16)acc1; o[2] = (bf16)acc2; o[3] = (bf16)acc3;
    o[4] = (bf16)acc4; o[5] = (bf16)acc5; o[6] = (bf16)acc6; o[7] = (bf16)acc7;
    *(bf16x8*)&s[(size_t)bn * CC + head * HDIM + q * 8] = o;
}

// ---------------- output proj: s[b][n][256] x Wout[256][256] + residual -> out[b][c][n] -----
__global__ __launch_bounds__(256) void outproj_mfma(const bf16* __restrict__ s_t,
                                                    const bf16* __restrict__ Wout,
                                                    const float* __restrict__ bout,
                                                    const float* __restrict__ query,
                                                    const float* __restrict__ pe,
                                                    float* __restrict__ out) {
    __shared__ bf16 As[128][72];
    __shared__ bf16 Bs[128][72];
    int tid = threadIdx.x, lane = tid & 63, wave = tid >> 6;
    int wm = wave >> 1, wn = wave & 1, g = lane >> 4, lr = lane & 15;
    int n0 = blockIdx.x * 128, c0 = blockIdx.y * 128, b = blockIdx.z;
    const bf16* sb = s_t + (size_t)b * CN * CC;
    f32x4 acc[4][4] = {};
    for (int k0 = 0; k0 < CC; k0 += 64) {
        stage_rows(sb + (size_t)n0 * CC + k0, As, 128, tid);
        stage_rows(Wout + (size_t)c0 * CC + k0, Bs, 128, tid);
        __syncthreads();
#pragma unroll
        for (int ks = 0; ks < 2; ++ks) {
            bf16x8 af[4], bfr[4];
#pragma unroll
            for (int mf = 0; mf < 4; ++mf)
                af[mf] = *(const bf16x8*)&As[wm * 64 + mf * 16 + lr][ks * 32 + g * 8];
#pragma unroll
            for (int nf = 0; nf < 4; ++nf)
                bfr[nf] = *(const bf16x8*)&Bs[wn * 64 + nf * 16 + lr][ks * 32 + g * 8];
#pragma unroll
            for (int mf = 0; mf < 4; ++mf)
#pragma unroll
                for (int nf = 0; nf < 4; ++nf)
                    acc[mf][nf] = MFMA16(af[mf], bfr[nf], acc[mf][nf]);
        }
        __syncthreads();
    }
#pragma unroll
    for (int mf = 0; mf < 4; ++mf) {
        int n = n0 + wm * 64 + mf * 16 + g * 4;
#pragma unroll
        for (int nf = 0; nf < 4; ++nf) {
            int c = c0 + wn * 64 + nf * 16 + lr;
            size_t base = ((size_t)b * CC + c) * CN + n;
            f32x4 q4 = *(const f32x4*)&query[base];
            f32x4 p4 = *(const f32x4*)&pe[(size_t)c * CN + n];
            float bias = bout[c];
            f32x4 r = acc[mf][nf];
#pragma unroll
            for (int j = 0; j < 4; ++j) r[j] = r[j] + bias + 2.0f * (q4[j] + p4[j]);
            *(f32x4*)&out[base] = r;
        }
    }
}

extern "C" void kernel_launch(void* const* d_in, const int* in_sizes, int n_in,
                              void* d_out, int out_size, void* d_ws, size_t ws_size,
                              hipStream_t stream) {
    const float* query = (const float*)d_in[0];
    const float* value = (const float*)d_in[1];
    const float* W_off = (const float*)d_in[2];
    const float* b_off = (const float*)d_in[3];
    const float* W_attn = (const float*)d_in[4];
    const float* b_attn = (const float*)d_in[5];
    const float* W_val = (const float*)d_in[6];
    const float* b_val = (const float*)d_in[7];
    const float* W_out = (const float*)d_in[8];
    const float* b_out = (const float*)d_in[9];
    float* out = (float*)d_out;

    char* p = (char*)d_ws;
    float* pe = (float*)p;            p += (size_t)CC * CN * 4;
    bf16* Wv_bf = (bf16*)p;           p += (size_t)CC * CC * 2;
    bf16* Wout_bf = (bf16*)p;         p += (size_t)CC * CC * 2;
    bf16* W96_bf = (bf16*)p;          p += (size_t)96 * CC * 2 + 256;
    bf16* val_t = (bf16*)p;           p += (size_t)CB * CN * CC * 2;
    bf16* qpe_t = (bf16*)p;           p += (size_t)CB * CN * CC * 2;
    bf16* v_s = (bf16*)p;             p += (size_t)CB * NHEADS * CN * HDIM * 2;
    float* oa = (float*)p;            p += (size_t)CB * CN * 96 * 4;
    bf16* s_t = (bf16*)p;             p += (size_t)CB * CN * CC * 2;

    pe_kernel<<<dim3((CC * CN + 255) / 256), dim3(256), 0, stream>>>(pe);
    pack_w<<<dim3(256), dim3(256), 0, stream>>>(W_val, W_off, W_attn, W_out,
                                                Wv_bf, W96_bf, Wout_bf);
    transpose_cvt<false><<<dim3(CN / 64, CC / 64, CB), dim3(256), 0, stream>>>(value, nullptr, val_t);
    transpose_cvt<true><<<dim3(CN / 64, CC / 64, CB), dim3(256), 0, stream>>>(query, pe, qpe_t);
    vproj_mfma<<<dim3(CN / 128, CC / 128, CB), dim3(256), 0, stream>>>(Wv_bf, b_val, val_t, v_s);
    offattn_mfma<<<dim3(CN / 128, 1, CB), dim3(256), 0, stream>>>(W96_bf, b_off, b_attn, qpe_t, oa);
    sample_kernel<<<dim3(CB * CN / SNB), dim3(256), 0, stream>>>(oa, v_s, s_t);
    outproj_mfma<<<dim3(CN / 128, CC / 128, CB), dim3(256), 0, stream>>>(s_t, Wout_bf, b_out,
                                                                         query, pe, out);
}

// Round 4
// 176.126 us; speedup vs baseline: 3.6171x; 1.1216x over previous
//
#include <hip/hip_runtime.h>
#include <hip/hip_bf16.h>

typedef __bf16 bf16;
typedef bf16 bf16x8 __attribute__((ext_vector_type(8)));
typedef bf16 bf16x4 __attribute__((ext_vector_type(4)));
typedef float f32x4 __attribute__((ext_vector_type(4)));

#define CB 16
#define CC 256
#define CH 64
#define CW 64
#define CN 4096
#define NHEADS 8
#define NPOINTS 4
#define HDIM 32
#define SNB 8   // n's per sampling block

#define MFMA16(a, b, c) __builtin_amdgcn_mfma_f32_16x16x32_bf16(a, b, c, 0, 0, 0)

// ---------------- PE table: pe[c][n] (f32) ----------------
__global__ __launch_bounds__(256) void pe_kernel(float* __restrict__ pe) {
    int idx = blockIdx.x * 256 + threadIdx.x;
    if (idx >= CC * CN) return;
    int c = idx >> 12, n = idx & (CN - 1);
    int r = n >> 6, x = n & 63;
    int i = c >> 2, t = c & 3;
    float div = __expf(-logf(10000.0f) * (float)i / 64.0f);
    float arg = ((t < 2) ? (float)(x + 1) : (float)(r + 1)) * div;
    pe[idx] = (t & 1) ? cosf(arg) : sinf(arg);
}

// ---------------- weight packing to bf16 ----------------
__global__ __launch_bounds__(256) void pack_w(const float* __restrict__ Wv,
                                              const float* __restrict__ Woff,
                                              const float* __restrict__ Wattn,
                                              const float* __restrict__ Wout,
                                              bf16* __restrict__ Wv_bf,
                                              bf16* __restrict__ W96_bf,
                                              bf16* __restrict__ Wout_bf) {
    int i = blockIdx.x * 256 + threadIdx.x;
    if (i < CC * CC) {
        Wv_bf[i] = (bf16)Wv[i];
        Wout_bf[i] = (bf16)Wout[i];
    }
    if (i < 96 * CC) {
        W96_bf[i] = (bf16)((i < 64 * CC) ? Woff[i] : Wattn[i - 64 * CC]);
    }
}

// ---------------- transpose + cvt: in[b][k][n] f32 (+pe) -> out[b][n][k] bf16 ----------------
template <bool ADD_PE>
__global__ __launch_bounds__(256) void transpose_cvt(const float* __restrict__ in,
                                                     const float* __restrict__ pe,
                                                     bf16* __restrict__ outp) {
    __shared__ float tile[64][65];
    int n0 = blockIdx.x * 64, k0 = blockIdx.y * 64, b = blockIdx.z;
    int tid = threadIdx.x;
    int tr = tid >> 4, tc = tid & 15;
    const float* src = in + ((size_t)b * CC + k0) * CN + n0;
#pragma unroll
    for (int p = 0; p < 4; ++p) {
        int k = p * 16 + tr;
        f32x4 v = *(const f32x4*)&src[(size_t)k * CN + tc * 4];
        if (ADD_PE) {
            f32x4 pv = *(const f32x4*)&pe[(size_t)(k0 + k) * CN + n0 + tc * 4];
            v += pv;
        }
#pragma unroll
        for (int j = 0; j < 4; ++j) tile[k][tc * 4 + j] = v[j];
    }
    __syncthreads();
#pragma unroll
    for (int p = 0; p < 4; ++p) {
        int n = p * 16 + tr;
        bf16x4 o;
#pragma unroll
        for (int j = 0; j < 4; ++j) o[j] = (bf16)tile[tc * 4 + j][n];
        *(bf16x4*)&outp[((size_t)b * CN + n0 + n) * CC + k0 + tc * 4] = o;
    }
}

// ---------------- shared staging helper: rows of [*][256] bf16 -> lds[row][72] ----------------
__device__ __forceinline__ void stage_rows(const bf16* __restrict__ src, bf16 (*lds)[72],
                                           int nrows, int tid) {
    for (int i = tid; i < nrows * 8; i += 256) {
        int row = i >> 3, ch = i & 7;
        uint4 v = *reinterpret_cast<const uint4*>(src + (size_t)row * CC + ch * 8);
        *reinterpret_cast<uint4*>(&lds[row][ch * 8]) = v;
    }
}

// ---------------- value projection: Wv[256][256] x act[b][n][256] -> v_s bf16 [b][h][n][dd] ----
__global__ __launch_bounds__(256) void vproj_mfma(const bf16* __restrict__ Wv,
                                                  const float* __restrict__ bv,
                                                  const bf16* __restrict__ act,
                                                  bf16* __restrict__ v_s) {
    __shared__ bf16 As[128][72];
    __shared__ bf16 Bs[128][72];
    int tid = threadIdx.x, lane = tid & 63, wave = tid >> 6;
    int wm = wave >> 1, wn = wave & 1, g = lane >> 4, lr = lane & 15;
    int n0 = blockIdx.x * 128, m0 = blockIdx.y * 128, b = blockIdx.z;
    const bf16* actb = act + (size_t)b * CN * CC;
    f32x4 acc[4][4] = {};
    for (int k0 = 0; k0 < CC; k0 += 64) {
        stage_rows(Wv + (size_t)m0 * CC + k0, As, 128, tid);
        stage_rows(actb + (size_t)n0 * CC + k0, Bs, 128, tid);
        __syncthreads();
#pragma unroll
        for (int ks = 0; ks < 2; ++ks) {
            bf16x8 af[4], bfr[4];
#pragma unroll
            for (int mf = 0; mf < 4; ++mf)
                af[mf] = *(const bf16x8*)&As[wm * 64 + mf * 16 + lr][ks * 32 + g * 8];
#pragma unroll
            for (int nf = 0; nf < 4; ++nf)
                bfr[nf] = *(const bf16x8*)&Bs[wn * 64 + nf * 16 + lr][ks * 32 + g * 8];
#pragma unroll
            for (int mf = 0; mf < 4; ++mf)
#pragma unroll
                for (int nf = 0; nf < 4; ++nf)
                    acc[mf][nf] = MFMA16(af[mf], bfr[nf], acc[mf][nf]);
        }
        __syncthreads();
    }
#pragma unroll
    for (int mf = 0; mf < 4; ++mf) {
        int co = m0 + wm * 64 + mf * 16 + g * 4;
        int head = co >> 5, dd = co & 31;
        float b0 = bv[co], b1 = bv[co + 1], b2 = bv[co + 2], b3 = bv[co + 3];
#pragma unroll
        for (int nf = 0; nf < 4; ++nf) {
            int n = n0 + wn * 64 + nf * 16 + lr;
            bf16x4 o;
            o[0] = (bf16)(acc[mf][nf][0] + b0);
            o[1] = (bf16)(acc[mf][nf][1] + b1);
            o[2] = (bf16)(acc[mf][nf][2] + b2);
            o[3] = (bf16)(acc[mf][nf][3] + b3);
            *(bf16x4*)&v_s[(((size_t)b * NHEADS + head) * CN + n) * HDIM + dd] = o;
        }
    }
}

// ---------------- off+attn: W96[96][256] x qpe[b][n][256] -> oa f32 [b][n][96] ----------------
__global__ __launch_bounds__(256) void offattn_mfma(const bf16* __restrict__ W96,
                                                    const float* __restrict__ boff,
                                                    const float* __restrict__ battn,
                                                    const bf16* __restrict__ qpe,
                                                    float* __restrict__ oa) {
    __shared__ bf16 As[96][72];
    __shared__ bf16 Bs[128][72];
    int tid = threadIdx.x, lane = tid & 63, wave = tid >> 6;
    int wm = wave >> 1, wn = wave & 1, g = lane >> 4, lr = lane & 15;
    int n0 = blockIdx.x * 128, b = blockIdx.z;
    const bf16* qb = qpe + (size_t)b * CN * CC;
    f32x4 acc[3][4] = {};
    for (int k0 = 0; k0 < CC; k0 += 64) {
        stage_rows(W96 + k0, As, 96, tid);
        stage_rows(qb + (size_t)n0 * CC + k0, Bs, 128, tid);
        __syncthreads();
#pragma unroll
        for (int ks = 0; ks < 2; ++ks) {
            bf16x8 af[3], bfr[4];
#pragma unroll
            for (int mf = 0; mf < 3; ++mf)
                af[mf] = *(const bf16x8*)&As[wm * 48 + mf * 16 + lr][ks * 32 + g * 8];
#pragma unroll
            for (int nf = 0; nf < 4; ++nf)
                bfr[nf] = *(const bf16x8*)&Bs[wn * 64 + nf * 16 + lr][ks * 32 + g * 8];
#pragma unroll
            for (int mf = 0; mf < 3; ++mf)
#pragma unroll
                for (int nf = 0; nf < 4; ++nf)
                    acc[mf][nf] = MFMA16(af[mf], bfr[nf], acc[mf][nf]);
        }
        __syncthreads();
    }
#pragma unroll
    for (int mf = 0; mf < 3; ++mf) {
        int j = wm * 48 + mf * 16 + g * 4;
        f32x4 bias;
#pragma unroll
        for (int r = 0; r < 4; ++r) {
            int jj = j + r;
            bias[r] = (jj < 64) ? boff[jj] : battn[jj - 64];
        }
#pragma unroll
        for (int nf = 0; nf < 4; ++nf) {
            int n = n0 + wn * 64 + nf * 16 + lr;
            f32x4 o = acc[mf][nf] + bias;
            *(f32x4*)&oa[((size_t)b * CN + n) * 96 + j] = o;
        }
    }
}

// ---------------- sampling: two-phase (weights once, wide gathers) -> s bf16 [b][n][256] ----
__global__ __launch_bounds__(256) void sample_kernel(const float* __restrict__ oa,
                                                     const bf16* __restrict__ v_s,
                                                     bf16* __restrict__ s) {
    __shared__ int   lidx[SNB][NHEADS][NPOINTS][4];
    __shared__ float lwgt[SNB][NHEADS][NPOINTS][4];
    int bn0 = blockIdx.x * SNB;
    int b = bn0 >> 12;
    int tid = threadIdx.x;

    // ---- phase 1: (nl, head, p) -> fold softmax*bilinear*validity into 4 corner weights ----
    {
        int nl = tid >> 5, head = (tid >> 2) & 7, p = tid & 3;
        int bn = bn0 + nl;
        int n = bn & (CN - 1);
        const float* oarow = oa + (size_t)bn * 96;
        f32x4 lg = *(const f32x4*)&oarow[64 + head * 4];
        float m = fmaxf(fmaxf(lg[0], lg[1]), fmaxf(lg[2], lg[3]));
        float e0 = __expf(lg[0] - m), e1 = __expf(lg[1] - m);
        float e2 = __expf(lg[2] - m), e3 = __expf(lg[3] - m);
        float ep = (p == 0) ? e0 : (p == 1) ? e1 : (p == 2) ? e2 : e3;
        float a = ep / (e0 + e1 + e2 + e3);

        float off0 = oarow[head * 8 + p * 2];
        float off1 = oarow[head * 8 + p * 2 + 1];
        float ix = (float)(n & 63) * (64.0f / 63.0f) + off0 - 0.5f;
        float iy = (float)(n >> 6) * (64.0f / 63.0f) + off1 - 0.5f;
        float x0f = floorf(ix), y0f = floorf(iy);
        float wx = ix - x0f, wy = iy - y0f;
        int x0 = (int)x0f, y0 = (int)y0f;
        int x1 = x0 + 1, y1 = y0 + 1;
        float vx0 = (x0 >= 0 && x0 < CW) ? 1.f : 0.f;
        float vx1 = (x1 >= 0 && x1 < CW) ? 1.f : 0.f;
        float vy0 = (y0 >= 0 && y0 < CH) ? 1.f : 0.f;
        float vy1 = (y1 >= 0 && y1 < CH) ? 1.f : 0.f;
        int x0c = min(max(x0, 0), CW - 1), x1c = min(max(x1, 0), CW - 1);
        int y0c = min(max(y0, 0), CH - 1), y1c = min(max(y1, 0), CH - 1);
        lwgt[nl][head][p][0] = a * (1.f - wx) * (1.f - wy) * vx0 * vy0;
        lwgt[nl][head][p][1] = a * wx * (1.f - wy) * vx1 * vy0;
        lwgt[nl][head][p][2] = a * (1.f - wx) * wy * vx0 * vy1;
        lwgt[nl][head][p][3] = a * wx * wy * vx1 * vy1;
        lidx[nl][head][p][0] = (y0c * CW + x0c) * HDIM;
        lidx[nl][head][p][1] = (y0c * CW + x1c) * HDIM;
        lidx[nl][head][p][2] = (y1c * CW + x0c) * HDIM;
        lidx[nl][head][p][3] = (y1c * CW + x1c) * HDIM;
    }
    __syncthreads();

    // ---- phase 2: (nl, head, q) -> 8 channels each, 16B gathers ----
    int nl = tid >> 5, head = (tid >> 2) & 7, q = tid & 3;
    int bn = bn0 + nl;
    const bf16* vb = v_s + (((size_t)b * NHEADS + head) * CN) * HDIM + q * 8;
    float acc0 = 0.f, acc1 = 0.f, acc2 = 0.f, acc3 = 0.f;
    float acc4 = 0.f, acc5 = 0.f, acc6 = 0.f, acc7 = 0.f;
#pragma unroll
    for (int p = 0; p < NPOINTS; ++p) {
#pragma unroll
        for (int c = 0; c < 4; ++c) {
            float w = lwgt[nl][head][p][c];
            int id = lidx[nl][head][p][c];
            bf16x8 v = *(const bf16x8*)&vb[id];
            acc0 += w * (float)v[0];
            acc1 += w * (float)v[1];
            acc2 += w * (float)v[2];
            acc3 += w * (float)v[3];
            acc4 += w * (float)v[4];
            acc5 += w * (float)v[5];
            acc6 += w * (float)v[6];
            acc7 += w * (float)v[7];
        }
    }
    bf16x8 o;
    o[0] = (bf16)acc0; o[1] = (bf16)acc1; o[2] = (bf16)acc2; o[3] = (bf16)acc3;
    o[4] = (bf16)acc4; o[5] = (bf16)acc5; o[6] = (bf16)acc6; o[7] = (bf16)acc7;
    *(bf16x8*)&s[(size_t)bn * CC + head * HDIM + q * 8] = o;
}

// ---------------- output proj: s[b][n][256] x Wout[256][256] + residual -> out[b][c][n] -----
// Epilogue drains acc through an LDS transpose so query/pe/out accesses are coalesced along n.
__global__ __launch_bounds__(256) void outproj_mfma(const bf16* __restrict__ s_t,
                                                    const bf16* __restrict__ Wout,
                                                    const float* __restrict__ bout,
                                                    const float* __restrict__ query,
                                                    const float* __restrict__ pe,
                                                    float* __restrict__ out) {
    __shared__ __align__(16) char smem[36864];
    bf16 (*As)[72] = (bf16(*)[72])smem;
    bf16 (*Bs)[72] = (bf16(*)[72])(smem + 128 * 72 * 2);
    float* T = (float*)smem;                 // [64][132] f32, reuses As/Bs after K-loop
    const int TP = 132;

    int tid = threadIdx.x, lane = tid & 63, wave = tid >> 6;
    int wm = wave >> 1, wn = wave & 1, g = lane >> 4, lr = lane & 15;
    int n0 = blockIdx.x * 128, c0 = blockIdx.y * 128, b = blockIdx.z;
    const bf16* sb = s_t + (size_t)b * CN * CC;
    f32x4 acc[4][4] = {};
    for (int k0 = 0; k0 < CC; k0 += 64) {
        stage_rows(sb + (size_t)n0 * CC + k0, As, 128, tid);
        stage_rows(Wout + (size_t)c0 * CC + k0, Bs, 128, tid);
        __syncthreads();
#pragma unroll
        for (int ks = 0; ks < 2; ++ks) {
            bf16x8 af[4], bfr[4];
#pragma unroll
            for (int mf = 0; mf < 4; ++mf)
                af[mf] = *(const bf16x8*)&As[wm * 64 + mf * 16 + lr][ks * 32 + g * 8];
#pragma unroll
            for (int nf = 0; nf < 4; ++nf)
                bfr[nf] = *(const bf16x8*)&Bs[wn * 64 + nf * 16 + lr][ks * 32 + g * 8];
#pragma unroll
            for (int mf = 0; mf < 4; ++mf)
#pragma unroll
                for (int nf = 0; nf < 4; ++nf)
                    acc[mf][nf] = MFMA16(af[mf], bfr[nf], acc[mf][nf]);
        }
        __syncthreads();
    }

    // drain c in two halves of 64 rows through LDS
    int lr5 = tid & 31, rq = tid >> 5;   // 32 lanes cover one 512B out-row; 8 rows/pass
#pragma unroll
    for (int ch = 0; ch < 2; ++ch) {
        if (wn == ch) {
#pragma unroll
            for (int mf = 0; mf < 4; ++mf)
#pragma unroll
                for (int nf = 0; nf < 4; ++nf) {
                    int cl = nf * 16 + lr;
                    int nl = wm * 64 + mf * 16 + g * 4;
                    *(f32x4*)&T[cl * TP + nl] = acc[mf][nf];
                }
        }
        __syncthreads();
#pragma unroll
        for (int pass = 0; pass < 8; ++pass) {
            int cl = pass * 8 + rq;
            int c = c0 + ch * 64 + cl;
            int n = n0 + lr5 * 4;
            f32x4 v = *(const f32x4*)&T[cl * TP + lr5 * 4];
            size_t base = ((size_t)b * CC + c) * CN + n;
            f32x4 q4 = *(const f32x4*)&query[base];
            f32x4 p4 = *(const f32x4*)&pe[(size_t)c * CN + n];
            float bias = bout[c];
#pragma unroll
            for (int j = 0; j < 4; ++j) v[j] = v[j] + bias + 2.0f * (q4[j] + p4[j]);
            *(f32x4*)&out[base] = v;
        }
        __syncthreads();
    }
}

extern "C" void kernel_launch(void* const* d_in, const int* in_sizes, int n_in,
                              void* d_out, int out_size, void* d_ws, size_t ws_size,
                              hipStream_t stream) {
    const float* query = (const float*)d_in[0];
    const float* value = (const float*)d_in[1];
    const float* W_off = (const float*)d_in[2];
    const float* b_off = (const float*)d_in[3];
    const float* W_attn = (const float*)d_in[4];
    const float* b_attn = (const float*)d_in[5];
    const float* W_val = (const float*)d_in[6];
    const float* b_val = (const float*)d_in[7];
    const float* W_out = (const float*)d_in[8];
    const float* b_out = (const float*)d_in[9];
    float* out = (float*)d_out;

    char* p = (char*)d_ws;
    float* pe = (float*)p;            p += (size_t)CC * CN * 4;
    bf16* Wv_bf = (bf16*)p;           p += (size_t)CC * CC * 2;
    bf16* Wout_bf = (bf16*)p;         p += (size_t)CC * CC * 2;
    bf16* W96_bf = (bf16*)p;          p += (size_t)96 * CC * 2 + 256;
    bf16* val_t = (bf16*)p;           p += (size_t)CB * CN * CC * 2;
    bf16* qpe_t = (bf16*)p;           p += (size_t)CB * CN * CC * 2;
    bf16* v_s = (bf16*)p;             p += (size_t)CB * NHEADS * CN * HDIM * 2;
    float* oa = (float*)p;            p += (size_t)CB * CN * 96 * 4;
    bf16* s_t = (bf16*)p;             p += (size_t)CB * CN * CC * 2;

    pe_kernel<<<dim3((CC * CN + 255) / 256), dim3(256), 0, stream>>>(pe);
    pack_w<<<dim3(256), dim3(256), 0, stream>>>(W_val, W_off, W_attn, W_out,
                                                Wv_bf, W96_bf, Wout_bf);
    transpose_cvt<false><<<dim3(CN / 64, CC / 64, CB), dim3(256), 0, stream>>>(value, nullptr, val_t);
    transpose_cvt<true><<<dim3(CN / 64, CC / 64, CB), dim3(256), 0, stream>>>(query, pe, qpe_t);
    vproj_mfma<<<dim3(CN / 128, CC / 128, CB), dim3(256), 0, stream>>>(Wv_bf, b_val, val_t, v_s);
    offattn_mfma<<<dim3(CN / 128, 1, CB), dim3(256), 0, stream>>>(W96_bf, b_off, b_attn, qpe_t, oa);
    sample_kernel<<<dim3(CB * CN / SNB), dim3(256), 0, stream>>>(oa, v_s, s_t);
    outproj_mfma<<<dim3(CN / 128, CC / 128, CB), dim3(256), 0, stream>>>(s_t, Wout_bf, b_out,
                                                                         query, pe, out);
}

// Round 5
// 167.136 us; speedup vs baseline: 3.8116x; 1.0538x over previous
//
#include <hip/hip_runtime.h>
#include <hip/hip_bf16.h>

typedef __bf16 bf16;
typedef bf16 bf16x8 __attribute__((ext_vector_type(8)));
typedef bf16 bf16x4 __attribute__((ext_vector_type(4)));
typedef float f32x4 __attribute__((ext_vector_type(4)));

#define CB 16
#define CC 256
#define CH 64
#define CW 64
#define CN 4096
#define NHEADS 8
#define NPOINTS 4
#define HDIM 32
#define SNB 8   // n's per sampling block

#define MFMA16(a, b, c) __builtin_amdgcn_mfma_f32_16x16x32_bf16(a, b, c, 0, 0, 0)

__device__ __forceinline__ int swzb(int row) { return ((row >> 3) & 7) << 4; }  // byte XOR

// ---------------- PE table: pe[c][n] (f32) ----------------
__global__ __launch_bounds__(256) void pe_kernel(float* __restrict__ pe) {
    int idx = blockIdx.x * 256 + threadIdx.x;
    if (idx >= CC * CN) return;
    int c = idx >> 12, n = idx & (CN - 1);
    int r = n >> 6, x = n & 63;
    int i = c >> 2, t = c & 3;
    float div = __expf(-logf(10000.0f) * (float)i / 64.0f);
    float arg = ((t < 2) ? (float)(x + 1) : (float)(r + 1)) * div;
    pe[idx] = (t & 1) ? cosf(arg) : sinf(arg);
}

// ---------------- weight packing to bf16 ----------------
__global__ __launch_bounds__(256) void pack_w(const float* __restrict__ Wv,
                                              const float* __restrict__ Woff,
                                              const float* __restrict__ Wattn,
                                              const float* __restrict__ Wout,
                                              bf16* __restrict__ Wv_bf,
                                              bf16* __restrict__ W96_bf,
                                              bf16* __restrict__ Wout_bf) {
    int i = blockIdx.x * 256 + threadIdx.x;
    if (i < CC * CC) {
        Wv_bf[i] = (bf16)Wv[i];
        Wout_bf[i] = (bf16)Wout[i];
    }
    if (i < 96 * CC) {
        W96_bf[i] = (bf16)((i < 64 * CC) ? Woff[i] : Wattn[i - 64 * CC]);
    }
}

// ---------------- shared staging helper: rows of [*][256] bf16 -> lds[row][72] ----------------
__device__ __forceinline__ void stage_rows(const bf16* __restrict__ src, bf16 (*lds)[72],
                                           int nrows, int tid) {
    for (int i = tid; i < nrows * 8; i += 256) {
        int row = i >> 3, ch = i & 7;
        uint4 v = *reinterpret_cast<const uint4*>(src + (size_t)row * CC + ch * 8);
        *reinterpret_cast<uint4*>(&lds[row][ch * 8]) = v;
    }
}

// ---------------- fused value projection: value[b][k][n] f32 -> v_s bf16 [b][h][n][dd] -------
// In-LDS transpose staging: F (f32 [64][132]) -> Bs (bf16 [128][72], XOR-swizzled).
// Weights read as direct global fragments (L2-resident). BM=256 (full CC), 512 threads.
__global__ __launch_bounds__(512) void vproj_f(const float* __restrict__ value,
                                               const bf16* __restrict__ Wv,
                                               const float* __restrict__ bv,
                                               bf16* __restrict__ v_s) {
    __shared__ float F[64][132];
    __shared__ bf16 Bs[128][72];
    char* BsC = (char*)&Bs[0][0];
    int tid = threadIdx.x, lane = tid & 63, wave = tid >> 6;
    int wm = wave >> 1, wn = wave & 1, g = lane >> 4, lr = lane & 15;
    int n0 = blockIdx.x * 128, b = blockIdx.z;
    const float* vb = value + (size_t)b * CC * CN + n0;

    int c32 = tid & 31, r = tid >> 5;           // stage1 mapping: 16 rows x (32 lanes * f32x4)
    f32x4 st[4];
#pragma unroll
    for (int p = 0; p < 4; ++p) st[p] = *(const f32x4*)&vb[(size_t)(p * 16 + r) * CN + c32 * 4];
#pragma unroll
    for (int p = 0; p < 4; ++p) *(f32x4*)&F[p * 16 + r][c32 * 4] = st[p];

    f32x4 acc[4][4] = {};
    for (int k0 = 0; k0 < CC; k0 += 64) {
        __syncthreads();                         // F ready
        {                                        // stage2: transpose F -> Bs (swizzled)
            int n = tid & 127, kq = tid >> 7;    // kq 0..3, 16 k's each
            float v[16];
#pragma unroll
            for (int i = 0; i < 16; ++i) v[i] = F[kq * 16 + i][n];
#pragma unroll
            for (int j = 0; j < 2; ++j) {
                bf16x8 o;
#pragma unroll
                for (int u = 0; u < 8; ++u) o[u] = (bf16)v[j * 8 + u];
                *(bf16x8*)(BsC + n * 144 + ((kq * 32 + j * 16) ^ swzb(n))) = o;
            }
        }
        __syncthreads();                         // Bs ready
        bool more = (k0 + 64 < CC);
        if (more) {                              // issue next-tile global loads (hide under MFMA)
#pragma unroll
            for (int p = 0; p < 4; ++p)
                st[p] = *(const f32x4*)&vb[(size_t)(k0 + 64 + p * 16 + r) * CN + c32 * 4];
        }
#pragma unroll
        for (int ks = 0; ks < 2; ++ks) {
            bf16x8 af[4], bfr[4];
#pragma unroll
            for (int mf = 0; mf < 4; ++mf)
                af[mf] = *(const bf16x8*)&Wv[(size_t)(wm * 64 + mf * 16 + lr) * CC + k0 + ks * 32 + g * 8];
#pragma unroll
            for (int nf = 0; nf < 4; ++nf) {
                int row = wn * 64 + nf * 16 + lr;
                bfr[nf] = *(const bf16x8*)(BsC + row * 144 + ((ks * 64 + g * 16) ^ swzb(row)));
            }
#pragma unroll
            for (int mf = 0; mf < 4; ++mf)
#pragma unroll
                for (int nf = 0; nf < 4; ++nf)
                    acc[mf][nf] = MFMA16(af[mf], bfr[nf], acc[mf][nf]);
        }
        if (more) {
#pragma unroll
            for (int p = 0; p < 4; ++p) *(f32x4*)&F[p * 16 + r][c32 * 4] = st[p];
        }
    }

    // ---- epilogue: drain acc through T (=F) so v_s writes are full 64B lines ----
    float* T = &F[0][0];
    int dn = tid >> 2, q = tid & 3;
#pragma unroll
    for (int pass = 0; pass < 4; ++pass) {
        __syncthreads();
        if (wm == pass) {
#pragma unroll
            for (int mf = 0; mf < 4; ++mf)
#pragma unroll
                for (int nf = 0; nf < 4; ++nf)
#pragma unroll
                    for (int i = 0; i < 4; ++i)
                        T[(mf * 16 + g * 4 + i) * 132 + wn * 64 + nf * 16 + lr] = acc[mf][nf][i];
        }
        __syncthreads();
#pragma unroll
        for (int j = 0; j < 2; ++j) {
            int cg = pass * 64 + q * 16 + j * 8;
            int head = cg >> 5, dd0 = cg & 31;
            bf16x8 o;
#pragma unroll
            for (int u = 0; u < 8; ++u)
                o[u] = (bf16)(T[(q * 16 + j * 8 + u) * 132 + dn] + bv[cg + u]);
            *(bf16x8*)&v_s[(((size_t)b * NHEADS + head) * CN + n0 + dn) * HDIM + dd0] = o;
        }
    }
}

// ---------------- fused off+attn: (query+pe)[b][k][n] -> oa f32 [b][96][n] -----------------
__global__ __launch_bounds__(256) void offattn_f(const float* __restrict__ query,
                                                 const float* __restrict__ pe,
                                                 const bf16* __restrict__ W96,
                                                 const float* __restrict__ boff,
                                                 const float* __restrict__ battn,
                                                 float* __restrict__ oa) {
    __shared__ float F[64][132];
    __shared__ bf16 Bs[128][72];
    char* BsC = (char*)&Bs[0][0];
    int tid = threadIdx.x, lane = tid & 63, wave = tid >> 6;
    int wm = wave >> 1, wn = wave & 1, g = lane >> 4, lr = lane & 15;
    int n0 = blockIdx.x * 128, b = blockIdx.z;
    const float* qb = query + (size_t)b * CC * CN + n0;
    const float* peb = pe + n0;

    int c32 = tid & 31, r = tid >> 5;           // r 0..7; 8 passes
    f32x4 st[8];
#pragma unroll
    for (int p = 0; p < 8; ++p) {
        size_t off = (size_t)(p * 8 + r) * CN + c32 * 4;
        st[p] = *(const f32x4*)&qb[off] + *(const f32x4*)&peb[off];
    }
#pragma unroll
    for (int p = 0; p < 8; ++p) *(f32x4*)&F[p * 8 + r][c32 * 4] = st[p];

    f32x4 acc[3][4] = {};
    for (int k0 = 0; k0 < CC; k0 += 64) {
        __syncthreads();
        {                                        // stage2: transpose
            int n = tid & 127, kh = tid >> 7;    // kh 0..1, 32 k's each
            float v[32];
#pragma unroll
            for (int i = 0; i < 32; ++i) v[i] = F[kh * 32 + i][n];
#pragma unroll
            for (int j = 0; j < 4; ++j) {
                bf16x8 o;
#pragma unroll
                for (int u = 0; u < 8; ++u) o[u] = (bf16)v[j * 8 + u];
                *(bf16x8*)(BsC + n * 144 + ((kh * 64 + j * 16) ^ swzb(n))) = o;
            }
        }
        __syncthreads();
        bool more = (k0 + 64 < CC);
        if (more) {
#pragma unroll
            for (int p = 0; p < 8; ++p) {
                size_t off = (size_t)(k0 + 64 + p * 8 + r) * CN + c32 * 4;
                st[p] = *(const f32x4*)&qb[off] + *(const f32x4*)&peb[off];
            }
        }
#pragma unroll
        for (int ks = 0; ks < 2; ++ks) {
            bf16x8 af[3], bfr[4];
#pragma unroll
            for (int mf = 0; mf < 3; ++mf)
                af[mf] = *(const bf16x8*)&W96[(size_t)(wm * 48 + mf * 16 + lr) * CC + k0 + ks * 32 + g * 8];
#pragma unroll
            for (int nf = 0; nf < 4; ++nf) {
                int row = wn * 64 + nf * 16 + lr;
                bfr[nf] = *(const bf16x8*)(BsC + row * 144 + ((ks * 64 + g * 16) ^ swzb(row)));
            }
#pragma unroll
            for (int mf = 0; mf < 3; ++mf)
#pragma unroll
                for (int nf = 0; nf < 4; ++nf)
                    acc[mf][nf] = MFMA16(af[mf], bfr[nf], acc[mf][nf]);
        }
        if (more) {
#pragma unroll
            for (int p = 0; p < 8; ++p) *(f32x4*)&F[p * 8 + r][c32 * 4] = st[p];
        }
    }
    // ---- epilogue: oa[b][96][n] — coalesced along n ----
#pragma unroll
    for (int mf = 0; mf < 3; ++mf) {
        int j0 = wm * 48 + mf * 16 + g * 4;
#pragma unroll
        for (int i = 0; i < 4; ++i) {
            int j = j0 + i;
            float bias = (j < 64) ? boff[j] : battn[j - 64];
#pragma unroll
            for (int nf = 0; nf < 4; ++nf) {
                int n = n0 + wn * 64 + nf * 16 + lr;
                oa[((size_t)b * 96 + j) * CN + n] = acc[mf][nf][i] + bias;
            }
        }
    }
}

// ---------------- sampling: two-phase -> s bf16 [b][n][256]; oa now [b][96][n] -------------
__global__ __launch_bounds__(256) void sample_kernel(const float* __restrict__ oa,
                                                     const bf16* __restrict__ v_s,
                                                     bf16* __restrict__ s) {
    __shared__ int   lidx[SNB][NHEADS][NPOINTS][4];
    __shared__ float lwgt[SNB][NHEADS][NPOINTS][4];
    int bn0 = blockIdx.x * SNB;
    int b = bn0 >> 12;
    int tid = threadIdx.x;
    const float* ob = oa + (size_t)b * 96 * CN;

    // ---- phase 1: (nl, head, p) ----
    {
        int nl = tid >> 5, head = (tid >> 2) & 7, p = tid & 3;
        int bn = bn0 + nl;
        int n = bn & (CN - 1);
        float lg0 = ob[(size_t)(64 + head * 4 + 0) * CN + n];
        float lg1 = ob[(size_t)(64 + head * 4 + 1) * CN + n];
        float lg2 = ob[(size_t)(64 + head * 4 + 2) * CN + n];
        float lg3 = ob[(size_t)(64 + head * 4 + 3) * CN + n];
        float m = fmaxf(fmaxf(lg0, lg1), fmaxf(lg2, lg3));
        float e0 = __expf(lg0 - m), e1 = __expf(lg1 - m);
        float e2 = __expf(lg2 - m), e3 = __expf(lg3 - m);
        float ep = (p == 0) ? e0 : (p == 1) ? e1 : (p == 2) ? e2 : e3;
        float a = ep / (e0 + e1 + e2 + e3);

        float off0 = ob[(size_t)(head * 8 + p * 2 + 0) * CN + n];
        float off1 = ob[(size_t)(head * 8 + p * 2 + 1) * CN + n];
        float ix = (float)(n & 63) * (64.0f / 63.0f) + off0 - 0.5f;
        float iy = (float)(n >> 6) * (64.0f / 63.0f) + off1 - 0.5f;
        float x0f = floorf(ix), y0f = floorf(iy);
        float wx = ix - x0f, wy = iy - y0f;
        int x0 = (int)x0f, y0 = (int)y0f;
        int x1 = x0 + 1, y1 = y0 + 1;
        float vx0 = (x0 >= 0 && x0 < CW) ? 1.f : 0.f;
        float vx1 = (x1 >= 0 && x1 < CW) ? 1.f : 0.f;
        float vy0 = (y0 >= 0 && y0 < CH) ? 1.f : 0.f;
        float vy1 = (y1 >= 0 && y1 < CH) ? 1.f : 0.f;
        int x0c = min(max(x0, 0), CW - 1), x1c = min(max(x1, 0), CW - 1);
        int y0c = min(max(y0, 0), CH - 1), y1c = min(max(y1, 0), CH - 1);
        lwgt[nl][head][p][0] = a * (1.f - wx) * (1.f - wy) * vx0 * vy0;
        lwgt[nl][head][p][1] = a * wx * (1.f - wy) * vx1 * vy0;
        lwgt[nl][head][p][2] = a * (1.f - wx) * wy * vx0 * vy1;
        lwgt[nl][head][p][3] = a * wx * wy * vx1 * vy1;
        lidx[nl][head][p][0] = (y0c * CW + x0c) * HDIM;
        lidx[nl][head][p][1] = (y0c * CW + x1c) * HDIM;
        lidx[nl][head][p][2] = (y1c * CW + x0c) * HDIM;
        lidx[nl][head][p][3] = (y1c * CW + x1c) * HDIM;
    }
    __syncthreads();

    // ---- phase 2: (nl, head, q) -> 8 channels each, 16B gathers ----
    int nl = tid >> 5, head = (tid >> 2) & 7, q = tid & 3;
    int bn = bn0 + nl;
    const bf16* vb = v_s + (((size_t)b * NHEADS + head) * CN) * HDIM + q * 8;
    float acc0 = 0.f, acc1 = 0.f, acc2 = 0.f, acc3 = 0.f;
    float acc4 = 0.f, acc5 = 0.f, acc6 = 0.f, acc7 = 0.f;
#pragma unroll
    for (int p = 0; p < NPOINTS; ++p) {
#pragma unroll
        for (int c = 0; c < 4; ++c) {
            float w = lwgt[nl][head][p][c];
            int id = lidx[nl][head][p][c];
            bf16x8 v = *(const bf16x8*)&vb[id];
            acc0 += w * (float)v[0];
            acc1 += w * (float)v[1];
            acc2 += w * (float)v[2];
            acc3 += w * (float)v[3];
            acc4 += w * (float)v[4];
            acc5 += w * (float)v[5];
            acc6 += w * (float)v[6];
            acc7 += w * (float)v[7];
        }
    }
    bf16x8 o;
    o[0] = (bf16)acc0; o[1] = (bf16)acc1; o[2] = (bf16)acc2; o[3] = (bf16)acc3;
    o[4] = (bf16)acc4; o[5] = (bf16)acc5; o[6] = (bf16)acc6; o[7] = (bf16)acc7;
    *(bf16x8*)&s[(size_t)bn * CC + head * HDIM + q * 8] = o;
}

// ---------------- output proj: s[b][n][256] x Wout[256][256] + residual -> out[b][c][n] -----
__global__ __launch_bounds__(256) void outproj_mfma(const bf16* __restrict__ s_t,
                                                    const bf16* __restrict__ Wout,
                                                    const float* __restrict__ bout,
                                                    const float* __restrict__ query,
                                                    const float* __restrict__ pe,
                                                    float* __restrict__ out) {
    __shared__ __align__(16) char smem[36864];
    bf16 (*As)[72] = (bf16(*)[72])smem;
    bf16 (*Bs)[72] = (bf16(*)[72])(smem + 128 * 72 * 2);
    float* T = (float*)smem;                 // [64][132] f32, reuses As/Bs after K-loop
    const int TP = 132;

    int tid = threadIdx.x, lane = tid & 63, wave = tid >> 6;
    int wm = wave >> 1, wn = wave & 1, g = lane >> 4, lr = lane & 15;
    int n0 = blockIdx.x * 128, c0 = blockIdx.y * 128, b = blockIdx.z;
    const bf16* sb = s_t + (size_t)b * CN * CC;
    f32x4 acc[4][4] = {};
    for (int k0 = 0; k0 < CC; k0 += 64) {
        stage_rows(sb + (size_t)n0 * CC + k0, As, 128, tid);
        stage_rows(Wout + (size_t)c0 * CC + k0, Bs, 128, tid);
        __syncthreads();
#pragma unroll
        for (int ks = 0; ks < 2; ++ks) {
            bf16x8 af[4], bfr[4];
#pragma unroll
            for (int mf = 0; mf < 4; ++mf)
                af[mf] = *(const bf16x8*)&As[wm * 64 + mf * 16 + lr][ks * 32 + g * 8];
#pragma unroll
            for (int nf = 0; nf < 4; ++nf)
                bfr[nf] = *(const bf16x8*)&Bs[wn * 64 + nf * 16 + lr][ks * 32 + g * 8];
#pragma unroll
            for (int mf = 0; mf < 4; ++mf)
#pragma unroll
                for (int nf = 0; nf < 4; ++nf)
                    acc[mf][nf] = MFMA16(af[mf], bfr[nf], acc[mf][nf]);
        }
        __syncthreads();
    }

    int lr5 = tid & 31, rq = tid >> 5;
#pragma unroll
    for (int ch = 0; ch < 2; ++ch) {
        if (wn == ch) {
#pragma unroll
            for (int mf = 0; mf < 4; ++mf)
#pragma unroll
                for (int nf = 0; nf < 4; ++nf) {
                    int cl = nf * 16 + lr;
                    int nl = wm * 64 + mf * 16 + g * 4;
                    *(f32x4*)&T[cl * TP + nl] = acc[mf][nf];
                }
        }
        __syncthreads();
#pragma unroll
        for (int pass = 0; pass < 8; ++pass) {
            int cl = pass * 8 + rq;
            int c = c0 + ch * 64 + cl;
            int n = n0 + lr5 * 4;
            f32x4 v = *(const f32x4*)&T[cl * TP + lr5 * 4];
            size_t base = ((size_t)b * CC + c) * CN + n;
            f32x4 q4 = *(const f32x4*)&query[base];
            f32x4 p4 = *(const f32x4*)&pe[(size_t)c * CN + n];
            float bias = bout[c];
#pragma unroll
            for (int j = 0; j < 4; ++j) v[j] = v[j] + bias + 2.0f * (q4[j] + p4[j]);
            *(f32x4*)&out[base] = v;
        }
        __syncthreads();
    }
}

extern "C" void kernel_launch(void* const* d_in, const int* in_sizes, int n_in,
                              void* d_out, int out_size, void* d_ws, size_t ws_size,
                              hipStream_t stream) {
    const float* query = (const float*)d_in[0];
    const float* value = (const float*)d_in[1];
    const float* W_off = (const float*)d_in[2];
    const float* b_off = (const float*)d_in[3];
    const float* W_attn = (const float*)d_in[4];
    const float* b_attn = (const float*)d_in[5];
    const float* W_val = (const float*)d_in[6];
    const float* b_val = (const float*)d_in[7];
    const float* W_out = (const float*)d_in[8];
    const float* b_out = (const float*)d_in[9];
    float* out = (float*)d_out;

    char* p = (char*)d_ws;
    float* pe = (float*)p;            p += (size_t)CC * CN * 4;
    bf16* Wv_bf = (bf16*)p;           p += (size_t)CC * CC * 2;
    bf16* Wout_bf = (bf16*)p;         p += (size_t)CC * CC * 2;
    bf16* W96_bf = (bf16*)p;          p += (size_t)96 * CC * 2 + 256;
    bf16* v_s = (bf16*)p;             p += (size_t)CB * NHEADS * CN * HDIM * 2;
    float* oa = (float*)p;            p += (size_t)CB * 96 * CN * 4;
    bf16* s_t = (bf16*)p;             p += (size_t)CB * CN * CC * 2;

    pe_kernel<<<dim3((CC * CN + 255) / 256), dim3(256), 0, stream>>>(pe);
    pack_w<<<dim3(256), dim3(256), 0, stream>>>(W_val, W_off, W_attn, W_out,
                                                Wv_bf, W96_bf, Wout_bf);
    vproj_f<<<dim3(CN / 128, 1, CB), dim3(512), 0, stream>>>(value, Wv_bf, b_val, v_s);
    offattn_f<<<dim3(CN / 128, 1, CB), dim3(256), 0, stream>>>(query, pe, W96_bf,
                                                               b_off, b_attn, oa);
    sample_kernel<<<dim3(CB * CN / SNB), dim3(256), 0, stream>>>(oa, v_s, s_t);
    outproj_mfma<<<dim3(CN / 128, CC / 128, CB), dim3(256), 0, stream>>>(s_t, Wout_bf, b_out,
                                                                         query, pe, out);
}